// Round 3
// baseline (51.247 us; speedup 1.0000x reference)
//
#include <hip/hip_runtime.h>
#include <cmath>

// RMSDLoss (batched Kabsch RMSD, mean over batch) — single fused kernel.
//  - LDS-staged, perfectly coalesced float4 loads (16B lane stride), decoupling
//    load layout from the 3-float atom layout (48B-stride loads were ~2x off BW).
//  - Per-atom consume from LDS: addr stride 12B -> bank stride 3 (odd) -> conflict-free.
//  - fp32 analytic 3x3 eigen-solve on thread 0 per block (proven absmax 0.0 in R2).
//  - mean via one atomicAdd per block into memset-zeroed d_out (no 2nd kernel).

constexpr int BLOCK = 256;
constexpr int NWAVE = BLOCK / 64;
constexpr int NS = 17;
constexpr int CHUNK_ATOMS = 1024;          // atoms per staged chunk
constexpr int CHUNK_F4    = 768;           // CHUNK_ATOMS*3/4 float4 per tensor

__global__ __launch_bounds__(BLOCK) void rmsd_fused_kernel(
    const float* __restrict__ yp,   // [B,N,3] coords (y_prime)
    const float* __restrict__ yr,   // [B,N,3] reference (y)
    float* __restrict__ out,        // [1] accumulated mean
    int n, float invB)
{
    __shared__ float lp[CHUNK_ATOMS * 3];   // 12 KB
    __shared__ float lq[CHUNK_ATOMS * 3];   // 12 KB
    const int b   = blockIdx.x;
    const int tid = threadIdx.x;
    const size_t row = (size_t)b * (size_t)n * 3u;
    const float4* p4 = (const float4*)(yp + row);
    const float4* q4 = (const float4*)(yr + row);
    float4* lp4 = (float4*)lp;
    float4* lq4 = (float4*)lq;

    float s1x=0.f,s1y=0.f,s1z=0.f, s2x=0.f,s2y=0.f,s2z=0.f, sq1=0.f,sq2=0.f;
    float c00=0.f,c01=0.f,c02=0.f,c10=0.f,c11=0.f,c12=0.f,c20=0.f,c21=0.f,c22=0.f;

    const int nchunks = n / CHUNK_ATOMS;
    for (int c = 0; c < nchunks; ++c) {
        const int base = c * CHUNK_F4;
        // Issue coalesced global loads BEFORE the reuse-barrier: HBM latency
        // hides under the barrier wait + LDS writes of other waves.
        float4 pa = p4[base + tid], pb = p4[base + tid + 256], pc = p4[base + tid + 512];
        float4 qa = q4[base + tid], qb = q4[base + tid + 256], qc = q4[base + tid + 512];
        if (c) __syncthreads();            // previous chunk fully consumed
        lp4[tid] = pa; lp4[tid + 256] = pb; lp4[tid + 512] = pc;
        lq4[tid] = qa; lq4[tid + 256] = qb; lq4[tid + 512] = qc;
        __syncthreads();

        #pragma unroll
        for (int k = 0; k < CHUNK_ATOMS / BLOCK; ++k) {
            const int a = tid + k * BLOCK;
            const float px = lp[3*a], py = lp[3*a+1], pz = lp[3*a+2];
            const float qx = lq[3*a], qy = lq[3*a+1], qz = lq[3*a+2];
            s1x += px; s1y += py; s1z += pz;
            s2x += qx; s2y += qy; s2z += qz;
            sq1 = fmaf(px,px, fmaf(py,py, fmaf(pz,pz, sq1)));
            sq2 = fmaf(qx,qx, fmaf(qy,qy, fmaf(qz,qz, sq2)));
            c00 = fmaf(px,qx,c00); c01 = fmaf(px,qy,c01); c02 = fmaf(px,qz,c02);
            c10 = fmaf(py,qx,c10); c11 = fmaf(py,qy,c11); c12 = fmaf(py,qz,c12);
            c20 = fmaf(pz,qx,c20); c21 = fmaf(pz,qy,c21); c22 = fmaf(pz,qz,c22);
        }
    }

    // Block reduction of the 17 sums.
    float vals[NS] = {s1x,s1y,s1z,s2x,s2y,s2z,sq1,sq2,
                      c00,c01,c02,c10,c11,c12,c20,c21,c22};
    __shared__ float sred[NWAVE][NS];
    const int wave = tid >> 6, lane = tid & 63;
    #pragma unroll
    for (int i = 0; i < NS; ++i) {
        float v = vals[i];
        #pragma unroll
        for (int off = 32; off > 0; off >>= 1) v += __shfl_down(v, off, 64);
        if (lane == 0) sred[wave][i] = v;
    }
    __syncthreads();

    if (tid == 0) {
        float t[NS];
        #pragma unroll
        for (int i = 0; i < NS; ++i) {
            float s = 0.f;
            #pragma unroll
            for (int w = 0; w < NWAVE; ++w) s += sred[w][i];
            t[i] = s;
        }
        const float fn = (float)n;
        const float m1x=t[0]/fn, m1y=t[1]/fn, m1z=t[2]/fn;
        const float m2x=t[3]/fn, m2y=t[4]/fn, m2z=t[5]/fn;
        const float E0 = (t[6] - fn*(m1x*m1x+m1y*m1y+m1z*m1z))
                       + (t[7] - fn*(m2x*m2x+m2y*m2y+m2z*m2z));
        const float A00=t[8] -fn*m1x*m2x, A01=t[9] -fn*m1x*m2y, A02=t[10]-fn*m1x*m2z;
        const float A10=t[11]-fn*m1y*m2x, A11=t[12]-fn*m1y*m2y, A12=t[13]-fn*m1y*m2z;
        const float A20=t[14]-fn*m1z*m2x, A21=t[15]-fn*m1z*m2y, A22=t[16]-fn*m1z*m2z;

        const float det = A00*(A11*A22-A12*A21)
                        - A01*(A10*A22-A12*A20)
                        + A02*(A10*A21-A11*A20);

        // G = A^T A (symmetric PSD); analytic eigenvalues (fp32)
        const float G00 = A00*A00+A10*A10+A20*A20;
        const float G01 = A00*A01+A10*A11+A20*A21;
        const float G02 = A00*A02+A10*A12+A20*A22;
        const float G11 = A01*A01+A11*A11+A21*A21;
        const float G12 = A01*A02+A11*A12+A21*A22;
        const float G22 = A02*A02+A12*A12+A22*A22;

        const float q  = (G00+G11+G22)*(1.f/3.f);
        const float p1 = G01*G01 + G02*G02 + G12*G12;
        const float p2 = (G00-q)*(G00-q)+(G11-q)*(G11-q)+(G22-q)*(G22-q) + 2.f*p1;
        const float p  = sqrtf(p2*(1.f/6.f));
        float e1, e2, e3;
        if (p < 1e-20f) {
            e1 = e2 = e3 = q;
        } else {
            const float ip = 1.f/p;
            const float C00=(G00-q)*ip, C01=G01*ip, C02=G02*ip;
            const float C11=(G11-q)*ip, C12=G12*ip, C22=(G22-q)*ip;
            float detC = C00*(C11*C22-C12*C12)
                       - C01*(C01*C22-C12*C02)
                       + C02*(C01*C12-C11*C02);
            float rr = fminf(1.f, fmaxf(-1.f, 0.5f*detC));
            const float phi = acosf(rr)*(1.f/3.f);
            e1 = q + 2.f*p*cosf(phi);
            e3 = q + 2.f*p*cosf(phi + 2.0943951023931953f);  // +2*pi/3
            e2 = 3.f*q - e1 - e3;
        }
        const float sv0 = sqrtf(fmaxf(e1,0.f));
        const float sv1 = sqrtf(fmaxf(e2,0.f));
        const float sv2 = sqrtf(fmaxf(e3,0.f));
        const float trs = sv0 + sv1 + ((det >= 0.f) ? sv2 : -sv2);
        const float msd = fmaxf(0.f, (E0 - 2.f*trs)/fn);
        atomicAdd(out, sqrtf(msd) * invB);
    }
}

extern "C" void kernel_launch(void* const* d_in, const int* in_sizes, int n_in,
                              void* d_out, int out_size, void* d_ws, size_t ws_size,
                              hipStream_t stream) {
    const float* yp = (const float*)d_in[0];   // y_prime [B,N,3] f32
    const float* yr = (const float*)d_in[1];   // y       [B,N,3] f32
    const int N = 2048;
    const int B = in_sizes[0] / (N * 3);

    hipMemsetAsync(d_out, 0, sizeof(float), stream);
    rmsd_fused_kernel<<<B, BLOCK, 0, stream>>>(yp, yr, (float*)d_out, N, 1.0f/(float)B);
}

// Round 4
// 48.298 us; speedup vs baseline: 1.0611x; 1.0611x over previous
//
#include <hip/hip_runtime.h>
#include <cmath>

// RMSDLoss (batched Kabsch RMSD, mean over batch) — single fused kernel.
//  - One atom per lane per load: 12B dwordx3, wave covers 768 contiguous bytes,
//    every byte used -> dense cache-line utilization (no LDS, no shuffles,
//    no barriers). R3's LDS staging was latency-serial at 2.5 blocks/CU.
//  - __launch_bounds__(256,8): VGPR<=64 so all 8 blocks/CU are co-resident
//    (grid 2048 = 256 CU x 8), 32 waves/CU hide HBM latency.
//  - fp32 analytic 3x3 eigen-solve on thread 0 (absmax 0.0 in R2/R3).
//  - mean via one atomicAdd per block into memset-zeroed d_out.

constexpr int BLOCK = 256;
constexpr int NWAVE = BLOCK / 64;
constexpr int NS = 17;

struct atom3 { float x, y, z; };   // 12B, 4B-aligned -> global_load_dwordx3

template<int N>
__global__ __launch_bounds__(BLOCK, 8) void rmsd_kernel(
    const float* __restrict__ yp,   // [B,N,3] coords (y_prime)
    const float* __restrict__ yr,   // [B,N,3] reference (y)
    float* __restrict__ out,        // [1] accumulated mean
    float invB)
{
    const int b   = blockIdx.x;
    const int tid = threadIdx.x;
    const atom3* p3 = (const atom3*)(yp + (size_t)b * (size_t)N * 3u);
    const atom3* q3 = (const atom3*)(yr + (size_t)b * (size_t)N * 3u);

    float s1x=0.f,s1y=0.f,s1z=0.f, s2x=0.f,s2y=0.f,s2z=0.f, sq1=0.f,sq2=0.f;
    float c00=0.f,c01=0.f,c02=0.f,c10=0.f,c11=0.f,c12=0.f,c20=0.f,c21=0.f,c22=0.f;

    #pragma unroll 2
    for (int a = tid; a < N; a += BLOCK) {
        const atom3 P = p3[a];
        const atom3 Q = q3[a];
        s1x += P.x; s1y += P.y; s1z += P.z;
        s2x += Q.x; s2y += Q.y; s2z += Q.z;
        sq1 = fmaf(P.x,P.x, fmaf(P.y,P.y, fmaf(P.z,P.z, sq1)));
        sq2 = fmaf(Q.x,Q.x, fmaf(Q.y,Q.y, fmaf(Q.z,Q.z, sq2)));
        c00 = fmaf(P.x,Q.x,c00); c01 = fmaf(P.x,Q.y,c01); c02 = fmaf(P.x,Q.z,c02);
        c10 = fmaf(P.y,Q.x,c10); c11 = fmaf(P.y,Q.y,c11); c12 = fmaf(P.y,Q.z,c12);
        c20 = fmaf(P.z,Q.x,c20); c21 = fmaf(P.z,Q.y,c21); c22 = fmaf(P.z,Q.z,c22);
    }

    // Block reduction of the 17 sums.
    float vals[NS] = {s1x,s1y,s1z,s2x,s2y,s2z,sq1,sq2,
                      c00,c01,c02,c10,c11,c12,c20,c21,c22};
    __shared__ float sred[NWAVE][NS];
    const int wave = tid >> 6, lane = tid & 63;
    #pragma unroll
    for (int i = 0; i < NS; ++i) {
        float v = vals[i];
        #pragma unroll
        for (int off = 32; off > 0; off >>= 1) v += __shfl_down(v, off, 64);
        if (lane == 0) sred[wave][i] = v;
    }
    __syncthreads();

    if (tid == 0) {
        float t[NS];
        #pragma unroll
        for (int i = 0; i < NS; ++i) {
            float s = 0.f;
            #pragma unroll
            for (int w = 0; w < NWAVE; ++w) s += sred[w][i];
            t[i] = s;
        }
        const float fn = (float)N;
        const float m1x=t[0]/fn, m1y=t[1]/fn, m1z=t[2]/fn;
        const float m2x=t[3]/fn, m2y=t[4]/fn, m2z=t[5]/fn;
        const float E0 = (t[6] - fn*(m1x*m1x+m1y*m1y+m1z*m1z))
                       + (t[7] - fn*(m2x*m2x+m2y*m2y+m2z*m2z));
        const float A00=t[8] -fn*m1x*m2x, A01=t[9] -fn*m1x*m2y, A02=t[10]-fn*m1x*m2z;
        const float A10=t[11]-fn*m1y*m2x, A11=t[12]-fn*m1y*m2y, A12=t[13]-fn*m1y*m2z;
        const float A20=t[14]-fn*m1z*m2x, A21=t[15]-fn*m1z*m2y, A22=t[16]-fn*m1z*m2z;

        const float det = A00*(A11*A22-A12*A21)
                        - A01*(A10*A22-A12*A20)
                        + A02*(A10*A21-A11*A20);

        // G = A^T A (symmetric PSD); analytic eigenvalues (fp32)
        const float G00 = A00*A00+A10*A10+A20*A20;
        const float G01 = A00*A01+A10*A11+A20*A21;
        const float G02 = A00*A02+A10*A12+A20*A22;
        const float G11 = A01*A01+A11*A11+A21*A21;
        const float G12 = A01*A02+A11*A12+A21*A22;
        const float G22 = A02*A02+A12*A12+A22*A22;

        const float q  = (G00+G11+G22)*(1.f/3.f);
        const float p1 = G01*G01 + G02*G02 + G12*G12;
        const float p2 = (G00-q)*(G00-q)+(G11-q)*(G11-q)+(G22-q)*(G22-q) + 2.f*p1;
        const float p  = sqrtf(p2*(1.f/6.f));
        float e1, e2, e3;
        if (p < 1e-20f) {
            e1 = e2 = e3 = q;
        } else {
            const float ip = 1.f/p;
            const float C00=(G00-q)*ip, C01=G01*ip, C02=G02*ip;
            const float C11=(G11-q)*ip, C12=G12*ip, C22=(G22-q)*ip;
            float detC = C00*(C11*C22-C12*C12)
                       - C01*(C01*C22-C12*C02)
                       + C02*(C01*C12-C11*C02);
            float rr = fminf(1.f, fmaxf(-1.f, 0.5f*detC));
            const float phi = acosf(rr)*(1.f/3.f);
            e1 = q + 2.f*p*cosf(phi);
            e3 = q + 2.f*p*cosf(phi + 2.0943951023931953f);  // +2*pi/3
            e2 = 3.f*q - e1 - e3;
        }
        const float sv0 = sqrtf(fmaxf(e1,0.f));
        const float sv1 = sqrtf(fmaxf(e2,0.f));
        const float sv2 = sqrtf(fmaxf(e3,0.f));
        const float trs = sv0 + sv1 + ((det >= 0.f) ? sv2 : -sv2);
        const float msd = fmaxf(0.f, (E0 - 2.f*trs)/fn);
        atomicAdd(out, sqrtf(msd) * invB);
    }
}

extern "C" void kernel_launch(void* const* d_in, const int* in_sizes, int n_in,
                              void* d_out, int out_size, void* d_ws, size_t ws_size,
                              hipStream_t stream) {
    const float* yp = (const float*)d_in[0];   // y_prime [B,N,3] f32
    const float* yr = (const float*)d_in[1];   // y       [B,N,3] f32
    const int N = 2048;
    const int B = in_sizes[0] / (N * 3);

    hipMemsetAsync(d_out, 0, sizeof(float), stream);
    rmsd_kernel<2048><<<B, BLOCK, 0, stream>>>(yp, yr, (float*)d_out, 1.0f/(float)B);
}

// Round 5
// 46.489 us; speedup vs baseline: 1.1023x; 1.0389x over previous
//
#include <hip/hip_runtime.h>
#include <cmath>

// RMSDLoss (batched Kabsch RMSD, mean over batch) — single fused kernel.
// R4 forensics: L3-resident replays ran at the SAME 47us as HBM-cold ones ->
// latency-bound, not BW-bound. Fix = maximal MLP: one block per row, each
// thread loads its full 8-atom share as 12 independent dwordx4 (12KB/wave in
// flight, straight-line, no loop-carried vmcnt). fp32 solve (absmax 0.0 in
// R2-R4), atomicAdd mean, no second kernel.

constexpr int BLOCK = 256;
constexpr int NWAVE = BLOCK / 64;
constexpr int NS = 17;

template<int N>
__global__ __launch_bounds__(BLOCK) void rmsd_kernel(
    const float* __restrict__ yp,   // [B,N,3] coords (y_prime)
    const float* __restrict__ yr,   // [B,N,3] reference (y)
    float* __restrict__ out,        // [1] accumulated mean
    float invB)
{
    static_assert(N == BLOCK * 8, "one thread = 8 atoms = 6 float4");
    const int b   = blockIdx.x;
    const int tid = threadIdx.x;
    const size_t row = (size_t)b * (size_t)N * 3u;
    const float4* p4 = (const float4*)(yp + row) + tid * 6;
    const float4* q4 = (const float4*)(yr + row) + tid * 6;

    // 12 independent loads, all issued before any consumption.
    const float4 P0=p4[0], P1=p4[1], P2=p4[2], P3=p4[3], P4=p4[4], P5=p4[5];
    const float4 Q0=q4[0], Q1=q4[1], Q2=q4[2], Q3=q4[3], Q4=q4[4], Q5=q4[5];

    float s1x=0.f,s1y=0.f,s1z=0.f, s2x=0.f,s2y=0.f,s2z=0.f, sq1=0.f,sq2=0.f;
    float c00=0.f,c01=0.f,c02=0.f,c10=0.f,c11=0.f,c12=0.f,c20=0.f,c21=0.f,c22=0.f;

    auto accum4 = [&](const float4&a0,const float4&a1,const float4&a2,
                      const float4&b0,const float4&b1,const float4&b2){
        float px[4]={a0.x,a0.w,a1.z,a2.y};
        float py[4]={a0.y,a1.x,a1.w,a2.z};
        float pz[4]={a0.z,a1.y,a2.x,a2.w};
        float qx[4]={b0.x,b0.w,b1.z,b2.y};
        float qy[4]={b0.y,b1.x,b1.w,b2.z};
        float qz[4]={b0.z,b1.y,b2.x,b2.w};
        #pragma unroll
        for (int k=0;k<4;k++){
            s1x+=px[k]; s1y+=py[k]; s1z+=pz[k];
            s2x+=qx[k]; s2y+=qy[k]; s2z+=qz[k];
            sq1 = fmaf(px[k],px[k], fmaf(py[k],py[k], fmaf(pz[k],pz[k], sq1)));
            sq2 = fmaf(qx[k],qx[k], fmaf(qy[k],qy[k], fmaf(qz[k],qz[k], sq2)));
            c00=fmaf(px[k],qx[k],c00); c01=fmaf(px[k],qy[k],c01); c02=fmaf(px[k],qz[k],c02);
            c10=fmaf(py[k],qx[k],c10); c11=fmaf(py[k],qy[k],c11); c12=fmaf(py[k],qz[k],c12);
            c20=fmaf(pz[k],qx[k],c20); c21=fmaf(pz[k],qy[k],c21); c22=fmaf(pz[k],qz[k],c22);
        }
    };
    accum4(P0,P1,P2, Q0,Q1,Q2);
    accum4(P3,P4,P5, Q3,Q4,Q5);

    // Block reduction of the 17 sums.
    float vals[NS] = {s1x,s1y,s1z,s2x,s2y,s2z,sq1,sq2,
                      c00,c01,c02,c10,c11,c12,c20,c21,c22};
    __shared__ float sred[NWAVE][NS];
    const int wave = tid >> 6, lane = tid & 63;
    #pragma unroll
    for (int i = 0; i < NS; ++i) {
        float v = vals[i];
        #pragma unroll
        for (int off = 32; off > 0; off >>= 1) v += __shfl_down(v, off, 64);
        if (lane == 0) sred[wave][i] = v;
    }
    __syncthreads();

    if (tid == 0) {
        float t[NS];
        #pragma unroll
        for (int i = 0; i < NS; ++i) {
            float s = 0.f;
            #pragma unroll
            for (int w = 0; w < NWAVE; ++w) s += sred[w][i];
            t[i] = s;
        }
        const float fn = (float)N;
        const float m1x=t[0]/fn, m1y=t[1]/fn, m1z=t[2]/fn;
        const float m2x=t[3]/fn, m2y=t[4]/fn, m2z=t[5]/fn;
        const float E0 = (t[6] - fn*(m1x*m1x+m1y*m1y+m1z*m1z))
                       + (t[7] - fn*(m2x*m2x+m2y*m2y+m2z*m2z));
        const float A00=t[8] -fn*m1x*m2x, A01=t[9] -fn*m1x*m2y, A02=t[10]-fn*m1x*m2z;
        const float A10=t[11]-fn*m1y*m2x, A11=t[12]-fn*m1y*m2y, A12=t[13]-fn*m1y*m2z;
        const float A20=t[14]-fn*m1z*m2x, A21=t[15]-fn*m1z*m2y, A22=t[16]-fn*m1z*m2z;

        const float det = A00*(A11*A22-A12*A21)
                        - A01*(A10*A22-A12*A20)
                        + A02*(A10*A21-A11*A20);

        // G = A^T A (symmetric PSD); analytic eigenvalues (fp32)
        const float G00 = A00*A00+A10*A10+A20*A20;
        const float G01 = A00*A01+A10*A11+A20*A21;
        const float G02 = A00*A02+A10*A12+A20*A22;
        const float G11 = A01*A01+A11*A11+A21*A21;
        const float G12 = A01*A02+A11*A12+A21*A22;
        const float G22 = A02*A02+A12*A12+A22*A22;

        const float q  = (G00+G11+G22)*(1.f/3.f);
        const float p1 = G01*G01 + G02*G02 + G12*G12;
        const float p2 = (G00-q)*(G00-q)+(G11-q)*(G11-q)+(G22-q)*(G22-q) + 2.f*p1;
        const float p  = sqrtf(p2*(1.f/6.f));
        float e1, e2, e3;
        if (p < 1e-20f) {
            e1 = e2 = e3 = q;
        } else {
            const float ip = 1.f/p;
            const float C00=(G00-q)*ip, C01=G01*ip, C02=G02*ip;
            const float C11=(G11-q)*ip, C12=G12*ip, C22=(G22-q)*ip;
            float detC = C00*(C11*C22-C12*C12)
                       - C01*(C01*C22-C12*C02)
                       + C02*(C01*C12-C11*C02);
            float rr = fminf(1.f, fmaxf(-1.f, 0.5f*detC));
            const float phi = acosf(rr)*(1.f/3.f);
            e1 = q + 2.f*p*cosf(phi);
            e3 = q + 2.f*p*cosf(phi + 2.0943951023931953f);  // +2*pi/3
            e2 = 3.f*q - e1 - e3;
        }
        const float sv0 = sqrtf(fmaxf(e1,0.f));
        const float sv1 = sqrtf(fmaxf(e2,0.f));
        const float sv2 = sqrtf(fmaxf(e3,0.f));
        const float trs = sv0 + sv1 + ((det >= 0.f) ? sv2 : -sv2);
        const float msd = fmaxf(0.f, (E0 - 2.f*trs)/fn);
        atomicAdd(out, sqrtf(msd) * invB);
    }
}

extern "C" void kernel_launch(void* const* d_in, const int* in_sizes, int n_in,
                              void* d_out, int out_size, void* d_ws, size_t ws_size,
                              hipStream_t stream) {
    const float* yp = (const float*)d_in[0];   // y_prime [B,N,3] f32
    const float* yr = (const float*)d_in[1];   // y       [B,N,3] f32
    const int N = 2048;
    const int B = in_sizes[0] / (N * 3);

    hipMemsetAsync(d_out, 0, sizeof(float), stream);
    rmsd_kernel<2048><<<B, BLOCK, 0, stream>>>(yp, yr, (float*)d_out, 1.0f/(float)B);
}

// Round 6
// 26.633 us; speedup vs baseline: 1.9242x; 1.7456x over previous
//
#include <hip/hip_runtime.h>
#include <cmath>

// RMSDLoss (batched Kabsch RMSD, mean over batch).
// R5 forensics: VGPR=32 proves regalloc re-serialized the 12-load burst
// (measured 1.2 TB/s == ~3KB/CU in flight / 600ns). Fix: sched_barrier(0)
// fence between load cluster and consumption forces all 12 dwordx4 live.
// Atomic same-address storm (~15us tail, data-independent) removed: kernel A
// stores rms[b], kernel B (1 block) does the mean. fp32 solve (absmax 0.0
// across R2-R5).

constexpr int BLOCK = 256;
constexpr int NWAVE = BLOCK / 64;
constexpr int NS = 17;

template<int N>
__global__ __launch_bounds__(BLOCK) void rmsd_kernel(
    const float* __restrict__ yp,   // [B,N,3] coords (y_prime)
    const float* __restrict__ yr,   // [B,N,3] reference (y)
    float* __restrict__ rms_out)    // [B]
{
    static_assert(N == BLOCK * 8, "one thread = 8 atoms = 6 float4");
    const int b   = blockIdx.x;
    const int tid = threadIdx.x;
    const size_t row = (size_t)b * (size_t)N * 3u;
    const float4* p4 = (const float4*)(yp + row) + tid * 6;
    const float4* q4 = (const float4*)(yr + row) + tid * 6;

    // 12 independent loads; the sched_barrier(0) fence below prevents the
    // scheduler from sinking any load past it -> all results simultaneously
    // live -> 12KB per wave in flight.
    const float4 P0=p4[0], P1=p4[1], P2=p4[2], P3=p4[3], P4=p4[4], P5=p4[5];
    const float4 Q0=q4[0], Q1=q4[1], Q2=q4[2], Q3=q4[3], Q4=q4[4], Q5=q4[5];
    __builtin_amdgcn_sched_barrier(0);

    float s1x=0.f,s1y=0.f,s1z=0.f, s2x=0.f,s2y=0.f,s2z=0.f, sq1=0.f,sq2=0.f;
    float c00=0.f,c01=0.f,c02=0.f,c10=0.f,c11=0.f,c12=0.f,c20=0.f,c21=0.f,c22=0.f;

    auto accum4 = [&](const float4&a0,const float4&a1,const float4&a2,
                      const float4&b0,const float4&b1,const float4&b2){
        float px[4]={a0.x,a0.w,a1.z,a2.y};
        float py[4]={a0.y,a1.x,a1.w,a2.z};
        float pz[4]={a0.z,a1.y,a2.x,a2.w};
        float qx[4]={b0.x,b0.w,b1.z,b2.y};
        float qy[4]={b0.y,b1.x,b1.w,b2.z};
        float qz[4]={b0.z,b1.y,b2.x,b2.w};
        #pragma unroll
        for (int k=0;k<4;k++){
            s1x+=px[k]; s1y+=py[k]; s1z+=pz[k];
            s2x+=qx[k]; s2y+=qy[k]; s2z+=qz[k];
            sq1 = fmaf(px[k],px[k], fmaf(py[k],py[k], fmaf(pz[k],pz[k], sq1)));
            sq2 = fmaf(qx[k],qx[k], fmaf(qy[k],qy[k], fmaf(qz[k],qz[k], sq2)));
            c00=fmaf(px[k],qx[k],c00); c01=fmaf(px[k],qy[k],c01); c02=fmaf(px[k],qz[k],c02);
            c10=fmaf(py[k],qx[k],c10); c11=fmaf(py[k],qy[k],c11); c12=fmaf(py[k],qz[k],c12);
            c20=fmaf(pz[k],qx[k],c20); c21=fmaf(pz[k],qy[k],c21); c22=fmaf(pz[k],qz[k],c22);
        }
    };
    accum4(P0,P1,P2, Q0,Q1,Q2);
    accum4(P3,P4,P5, Q3,Q4,Q5);

    // Block reduction of the 17 sums.
    float vals[NS] = {s1x,s1y,s1z,s2x,s2y,s2z,sq1,sq2,
                      c00,c01,c02,c10,c11,c12,c20,c21,c22};
    __shared__ float sred[NWAVE][NS];
    const int wave = tid >> 6, lane = tid & 63;
    #pragma unroll
    for (int i = 0; i < NS; ++i) {
        float v = vals[i];
        #pragma unroll
        for (int off = 32; off > 0; off >>= 1) v += __shfl_down(v, off, 64);
        if (lane == 0) sred[wave][i] = v;
    }
    __syncthreads();

    if (tid == 0) {
        float t[NS];
        #pragma unroll
        for (int i = 0; i < NS; ++i) {
            float s = 0.f;
            #pragma unroll
            for (int w = 0; w < NWAVE; ++w) s += sred[w][i];
            t[i] = s;
        }
        const float fn = (float)N;
        const float m1x=t[0]/fn, m1y=t[1]/fn, m1z=t[2]/fn;
        const float m2x=t[3]/fn, m2y=t[4]/fn, m2z=t[5]/fn;
        const float E0 = (t[6] - fn*(m1x*m1x+m1y*m1y+m1z*m1z))
                       + (t[7] - fn*(m2x*m2x+m2y*m2y+m2z*m2z));
        const float A00=t[8] -fn*m1x*m2x, A01=t[9] -fn*m1x*m2y, A02=t[10]-fn*m1x*m2z;
        const float A10=t[11]-fn*m1y*m2x, A11=t[12]-fn*m1y*m2y, A12=t[13]-fn*m1y*m2z;
        const float A20=t[14]-fn*m1z*m2x, A21=t[15]-fn*m1z*m2y, A22=t[16]-fn*m1z*m2z;

        const float det = A00*(A11*A22-A12*A21)
                        - A01*(A10*A22-A12*A20)
                        + A02*(A10*A21-A11*A20);

        // G = A^T A (symmetric PSD); analytic eigenvalues (fp32)
        const float G00 = A00*A00+A10*A10+A20*A20;
        const float G01 = A00*A01+A10*A11+A20*A21;
        const float G02 = A00*A02+A10*A12+A20*A22;
        const float G11 = A01*A01+A11*A11+A21*A21;
        const float G12 = A01*A02+A11*A12+A21*A22;
        const float G22 = A02*A02+A12*A12+A22*A22;

        const float q  = (G00+G11+G22)*(1.f/3.f);
        const float p1 = G01*G01 + G02*G02 + G12*G12;
        const float p2 = (G00-q)*(G00-q)+(G11-q)*(G11-q)+(G22-q)*(G22-q) + 2.f*p1;
        const float p  = sqrtf(p2*(1.f/6.f));
        float e1, e2, e3;
        if (p < 1e-20f) {
            e1 = e2 = e3 = q;
        } else {
            const float ip = 1.f/p;
            const float C00=(G00-q)*ip, C01=G01*ip, C02=G02*ip;
            const float C11=(G11-q)*ip, C12=G12*ip, C22=(G22-q)*ip;
            float detC = C00*(C11*C22-C12*C12)
                       - C01*(C01*C22-C12*C02)
                       + C02*(C01*C12-C11*C02);
            float rr = fminf(1.f, fmaxf(-1.f, 0.5f*detC));
            const float phi = acosf(rr)*(1.f/3.f);
            e1 = q + 2.f*p*cosf(phi);
            e3 = q + 2.f*p*cosf(phi + 2.0943951023931953f);  // +2*pi/3
            e2 = 3.f*q - e1 - e3;
        }
        const float sv0 = sqrtf(fmaxf(e1,0.f));
        const float sv1 = sqrtf(fmaxf(e2,0.f));
        const float sv2 = sqrtf(fmaxf(e3,0.f));
        const float trs = sv0 + sv1 + ((det >= 0.f) ? sv2 : -sv2);
        const float msd = fmaxf(0.f, (E0 - 2.f*trs)/fn);
        rms_out[b] = sqrtf(msd);
    }
}

__global__ __launch_bounds__(BLOCK) void mean_kernel(
    const float* __restrict__ rms, float* __restrict__ out, int B)
{
    const int tid = threadIdx.x;
    const float4* r4 = (const float4*)rms;
    float s = 0.f;
    for (int i = tid; i < B/4; i += BLOCK) {
        float4 v = r4[i];
        s += (v.x + v.y) + (v.z + v.w);
    }
    #pragma unroll
    for (int off = 32; off > 0; off >>= 1) s += __shfl_down(s, off, 64);
    __shared__ float sred[NWAVE];
    const int wave = tid >> 6, lane = tid & 63;
    if (lane == 0) sred[wave] = s;
    __syncthreads();
    if (tid == 0) {
        float tot = 0.f;
        #pragma unroll
        for (int w = 0; w < NWAVE; ++w) tot += sred[w];
        out[0] = tot / (float)B;
    }
}

extern "C" void kernel_launch(void* const* d_in, const int* in_sizes, int n_in,
                              void* d_out, int out_size, void* d_ws, size_t ws_size,
                              hipStream_t stream) {
    const float* yp = (const float*)d_in[0];   // y_prime [B,N,3] f32
    const float* yr = (const float*)d_in[1];   // y       [B,N,3] f32
    const int N = 2048;
    const int B = in_sizes[0] / (N * 3);
    float* rms_ws = (float*)d_ws;              // B floats

    rmsd_kernel<2048><<<B, BLOCK, 0, stream>>>(yp, yr, rms_ws);
    mean_kernel<<<1, BLOCK, 0, stream>>>(rms_ws, (float*)d_out, B);
}